// Round 3
// baseline (256.855 us; speedup 1.0000x reference)
//
#include <hip/hip_runtime.h>
#include <hip/hip_fp16.h>

#define Mpts 32768
#define Vv 9
#define Cc 24
#define Hh 120
#define Ww 160
#define Npts (Mpts * 8)          // 262144
#define PIX (Hh * Ww)            // 19200
#define VOXEL 0.04f

// ---------------- workspace layout (bytes) ----------------
// [0,64)    : 3 doubles: sum_z, sum_z2, pos_cnt (zeroed by prep)
// OFF_TF    : tf = feats (V,H,W) x 32B/pixel fp8(24ch+8pad) : 5529600 B
// OFF_PREH  : pre_h (M,24) f32                               : 3145728 B
// OFF_HP    : hp (12,N) uint (= half2 channel pairs)         : 12582912 B
// OFF_Z     : zbuf (N) f32                                   : 1048576 B
#define OFF_TF    64
#define OFF_PREH  (OFF_TF + Vv * PIX * 32)
#define OFF_HP    (OFF_PREH + Mpts * Cc * 4)
#define OFF_Z     (OFF_HP + Npts * Cc * 2)

typedef __attribute__((ext_vector_type(2))) float f32x2;

__device__ __forceinline__ unsigned pack2h(float a, float b) {
  __half2 h = __floats2half2_rn(a, b);
  return *(unsigned*)&h;
}

// pack 4 floats -> 4 fp8 e4m3 in one uint
__device__ __forceinline__ unsigned pack4fp8(float a, float b, float c,
                                             float d) {
  int u = __builtin_amdgcn_cvt_pk_fp8_f32(a, b, 0, false);
  u = __builtin_amdgcn_cvt_pk_fp8_f32(c, d, u, true);
  return (unsigned)u;
}

// ---------------- 1) prep (merged): tf-convert OR pre_h gemm ---------------
__global__ __launch_bounds__(256) void prep_kernel(
    const float* __restrict__ feats, const float* __restrict__ pre_feat,
    const float* __restrict__ W_sp, const float* __restrict__ b_sp,
    uint4* __restrict__ tf, float* __restrict__ pre_h,
    double* __restrict__ red) {
  __shared__ float tile[64][Cc + 1];   // 6.4 KB (tf path)
  __shared__ float P[256 * 50];        // 51.2 KB (gemm path)
  __shared__ float Wl[50 * Cc];        // 4.8 KB
  __shared__ float bl[Cc];
  int blk = blockIdx.x;
  if (blk == 0 && threadIdx.x < 3) red[threadIdx.x] = 0.0;

  if (blk < Vv * 300) {
    int v = blk / 300;
    int p0 = (blk % 300) * 64;
    const float* src = feats + (size_t)v * (Cc * PIX);
    for (int i = threadIdx.x; i < Cc * 64; i += 256) {
      int c = i >> 6, p = i & 63;
      tile[p][c] = src[c * PIX + p0 + p];
    }
    __syncthreads();
    uint4* dst = tf + ((size_t)v * PIX + p0) * 2;
    if (threadIdx.x < 128) {
      int p = threadIdx.x >> 1, sel = threadIdx.x & 1;
      const float* t = &tile[p][0];
      uint4 u;
      if (sel == 0) {
        u.x = pack4fp8(t[0], t[1], t[2], t[3]);
        u.y = pack4fp8(t[4], t[5], t[6], t[7]);
        u.z = pack4fp8(t[8], t[9], t[10], t[11]);
        u.w = pack4fp8(t[12], t[13], t[14], t[15]);
      } else {
        u.x = pack4fp8(t[16], t[17], t[18], t[19]);
        u.y = pack4fp8(t[20], t[21], t[22], t[23]);
        u.z = 0;
        u.w = 0;
      }
      dst[p * 2 + sel] = u;
    }
  } else {
    int mb = blk - Vv * 300;
    const float4* src4 = (const float4*)(pre_feat + (size_t)mb * (256 * 50));
    for (int i = threadIdx.x; i < (256 * 50) / 4; i += 256)
      ((float4*)P)[i] = src4[i];
    for (int i = threadIdx.x; i < 50 * Cc; i += 256) Wl[i] = W_sp[25 * Cc + i];
    if (threadIdx.x < Cc) bl[threadIdx.x] = b_sp[threadIdx.x];
    __syncthreads();

    float acc[Cc];
#pragma unroll
    for (int j = 0; j < Cc; j++) acc[j] = bl[j];
    const float2* row = (const float2*)&P[threadIdx.x * 50];
#pragma unroll
    for (int k = 0; k < 25; k++) {
      float2 x = row[k];
#pragma unroll
      for (int j = 0; j < Cc; j++)
        acc[j] += x.x * Wl[(2 * k) * Cc + j] + x.y * Wl[(2 * k + 1) * Cc + j];
    }
    float4* o4 = (float4*)(pre_h + ((size_t)mb * 256 + threadIdx.x) * Cc);
    o4[0] = make_float4(acc[0], acc[1], acc[2], acc[3]);
    o4[1] = make_float4(acc[4], acc[5], acc[6], acc[7]);
    o4[2] = make_float4(acc[8], acc[9], acc[10], acc[11]);
    o4[3] = make_float4(acc[12], acc[13], acc[14], acc[15]);
    o4[4] = make_float4(acc[16], acc[17], acc[18], acc[19]);
    o4[5] = make_float4(acc[20], acc[21], acc[22], acc[23]);
  }
}

// acc[0..15] += w * fp8x16(A)
__device__ __forceinline__ void acc16(uint4 A, float w, float* acc) {
#pragma unroll
  for (int t = 0; t < 4; t++) {
    unsigned u = ((const unsigned*)&A)[t];
    f32x2 f0 = __builtin_amdgcn_cvt_pk_f32_fp8((int)u, false);
    f32x2 f1 = __builtin_amdgcn_cvt_pk_f32_fp8((int)u, true);
    acc[4 * t + 0] += w * f0.x;
    acc[4 * t + 1] += w * f0.y;
    acc[4 * t + 2] += w * f1.x;
    acc[4 * t + 3] += w * f1.y;
  }
}
// acc[0..7] += w * fp8x8(ux,uy)
__device__ __forceinline__ void acc8v(unsigned ux, unsigned uy, float w,
                                      float* acc) {
  f32x2 f0 = __builtin_amdgcn_cvt_pk_f32_fp8((int)ux, false);
  f32x2 f1 = __builtin_amdgcn_cvt_pk_f32_fp8((int)ux, true);
  f32x2 f2 = __builtin_amdgcn_cvt_pk_f32_fp8((int)uy, false);
  f32x2 f3 = __builtin_amdgcn_cvt_pk_f32_fp8((int)uy, true);
  acc[0] += w * f0.x;
  acc[1] += w * f0.y;
  acc[2] += w * f1.x;
  acc[3] += w * f1.y;
  acc[4] += w * f2.x;
  acc[5] += w * f2.y;
  acc[6] += w * f3.x;
  acc[7] += w * f3.y;
}

// ---------------- main: 2 lanes/point split by BILINEAR ROW ----------------
// q=0 lane: corners (xs,ys),(xs+1,ys); q=1 lane: (xs,ys+1),(xs+1,ys+1).
// Both lanes iterate ALL views in lockstep -> per-wave gather locality
// identical to the 1-thread/point version, but 2x wave supply and a halved
// per-thread load chain. acc combined via shfl_xor(1); zsum/cnt replicated.
struct VS {
  const uint4* p;   // this thread's row base (corner xs)
  float wA, wB;     // weights for corners xs / xs+1 in this row
  float izm;
  int mski;
};

__device__ __forceinline__ VS project2(int v, const float* KR,
                                       const uint4* tfq, float wx0, float wy0,
                                       float wz0, int q) {
  const float* kr = &KR[v * 12];
  float ix = kr[0] * wx0 + kr[1] * wy0 + kr[2] * wz0 + kr[3];
  float iy = kr[4] * wx0 + kr[5] * wy0 + kr[6] * wz0 + kr[7];
  float iz = kr[8] * wx0 + kr[9] * wy0 + kr[10] * wz0 + kr[11];
  float sz = (fabsf(iz) > 1e-9f) ? iz : 1e-9f;
  float rs = 1.f / sz;
  float px = ix * rs;
  float py = iy * rs;
  bool msk = (px >= 0.f) && (px <= (float)(Ww - 1)) && (py >= 0.f) &&
             (py <= (float)(Hh - 1)) && (iz > 0.f);
  float pxc = fminf(fmaxf(px, 0.f), (float)(Ww - 1));
  float pyc = fminf(fmaxf(py, 0.f), (float)(Hh - 1));
  int xs = min((int)pxc, Ww - 2);
  int ys = min((int)pyc, Hh - 2);
  float wx = pxc - (float)xs, wy = pyc - (float)ys;
  float wm = msk ? 1.f : 0.f;
  float fy = q ? wy : (1.f - wy);  // row weight for this lane
  VS s;
  s.wA = (1.f - wx) * fy * wm;
  s.wB = wx * fy * wm;
  int pix = msk ? ((ys + q) * Ww + xs) : 0;
  s.p = tfq + ((size_t)(v * PIX + pix)) * 2;
  s.izm = msk ? iz : 0.f;
  s.mski = msk ? 1 : 0;
  return s;
}

struct GB {
  uint4 a;   // corner xs   ch0-15
  uint2 ab;  // corner xs   ch16-23
  uint4 b;   // corner xs+1 ch0-15
  uint2 bb;  // corner xs+1 ch16-23
};

__device__ __forceinline__ GB gload2(const VS& s) {
  GB g;
  g.a = s.p[0];
  g.ab = *(const uint2*)(s.p + 1);
  g.b = s.p[2];
  g.bb = *(const uint2*)(s.p + 3);
  return g;
}

__device__ __forceinline__ void gacc2(const GB& g, const VS& s, float* acc) {
  acc16(g.a, s.wA, acc);
  acc8v(g.ab.x, g.ab.y, s.wA, acc + 16);
  acc16(g.b, s.wB, acc);
  acc8v(g.bb.x, g.bb.y, s.wB, acc + 16);
}

__global__ __launch_bounds__(256) void main_kernel(
    const int* __restrict__ pre_coords, const uint4* __restrict__ tfq,
    const float* __restrict__ KRcam, const float* __restrict__ vol_origin,
    const float* __restrict__ w2ac, const float* __restrict__ W_sp,
    const float* __restrict__ pre_h, float* __restrict__ out,
    unsigned* __restrict__ hp, float* __restrict__ zbuf,
    double* __restrict__ red) {
  __shared__ float KR[Vv * 12];
  __shared__ float w2a[12];
  __shared__ float orig[3];
  __shared__ float redl[3][4];
  for (int i = threadIdx.x; i < Vv * 12; i += 256) {
    int v = i / 12, r = i - v * 12;
    KR[i] = KRcam[v * 16 + r];
  }
  if (threadIdx.x < 12) w2a[threadIdx.x] = w2ac[threadIdx.x];
  if (threadIdx.x < 3) orig[threadIdx.x] = vol_origin[threadIdx.x];
  __syncthreads();

  int g = blockIdx.x * 256 + threadIdx.x;
  int n = g >> 1;  // point index
  int q = g & 1;   // bilinear row parity
  int m = n >> 3, o = n & 7;
  int4 pc = ((const int4*)pre_coords)[m];
  int cx = pc.y + ((0xB2 >> o) & 1);
  int cy = pc.z + ((0xD4 >> o) & 1);
  int cz = pc.w + ((0xE8 >> o) & 1);
  float wx0 = (float)cx * VOXEL + orig[0];
  float wy0 = (float)cy * VOXEL + orig[1];
  float wz0 = (float)cz * VOXEL + orig[2];

  if (q == 0) {  // r_coords (one write per point)
    float camx = w2a[0] * wx0 + w2a[1] * wy0 + w2a[2] * wz0 + w2a[3];
    float camy = w2a[4] * wx0 + w2a[5] * wy0 + w2a[6] * wz0 + w2a[7];
    float camz = w2a[8] * wx0 + w2a[9] * wy0 + w2a[10] * wz0 + w2a[11];
    float4 rc = make_float4(camx, camy, camz, (float)pc.x);
    ((float4*)(out + 3 * (size_t)Npts))[n] = rc;
  }

  float acc[Cc];
#pragma unroll
  for (int c = 0; c < Cc; c++) acc[c] = 0.f;
  float zsum = 0.f;
  int cnt = 0;

  // depth-2 pipelined view loop (fully unrolled, static buffer indices)
  VS st[2];
  GB gb[2];
  st[0] = project2(0, KR, tfq, wx0, wy0, wz0, q);
  gb[0] = gload2(st[0]);
  st[1] = project2(1, KR, tfq, wx0, wy0, wz0, q);
  gb[1] = gload2(st[1]);
#pragma unroll
  for (int k = 0; k < Vv; k++) {
    int b = k & 1;
    gacc2(gb[b], st[b], acc);
    zsum += st[b].izm;
    cnt += st[b].mski;
    if (k + 2 < Vv) {
      st[b] = project2(k + 2, KR, tfq, wx0, wy0, wz0, q);
      gb[b] = gload2(st[b]);
    }
  }

  // combine the two bilinear rows (lanes 2i / 2i+1 hold the same point)
#pragma unroll
  for (int c = 0; c < Cc; c++) acc[c] += __shfl_xor(acc[c], 1);
  // zsum / cnt are identical on both lanes (same projections) - no combine.

  float denom = fmaxf((float)cnt, 1.f);
  float invd = 1.f / denom;
  float z = zsum * invd;

  // h = (acc*invd) @ W_sp[0:24,:]  (redundant on both lanes; W_sp offsets are
  // thread-uniform compile-time constants -> scalar loads)
  float h[Cc];
#pragma unroll
  for (int j = 0; j < Cc; j++) h[j] = 0.f;
#pragma unroll
  for (int c = 0; c < Cc; c++) {
    float f = acc[c] * invd;
#pragma unroll
    for (int j = 0; j < Cc; j++) h[j] += f * W_sp[c * Cc + j];
  }

  // pre_h split by parity: even lane ch 0..11, odd lane ch 12..23
  const float4* ph4 = (const float4*)(pre_h + (size_t)m * Cc + q * 12);
  float4 pa = ph4[0], pb = ph4[1], pcv = ph4[2];
  float phv[12] = {pa.x, pa.y, pa.z, pa.w,  pb.x,  pb.y,
                   pb.z, pb.w, pcv.x, pcv.y, pcv.z, pcv.w};

  if (q == 0) {
#pragma unroll
    for (int j2 = 0; j2 < 6; j2++)
      hp[(size_t)j2 * Npts + n] =
          pack2h(h[2 * j2] + phv[2 * j2], h[2 * j2 + 1] + phv[2 * j2 + 1]);
  } else {
#pragma unroll
    for (int j2 = 0; j2 < 6; j2++)
      hp[(size_t)(6 + j2) * Npts + n] = pack2h(
          h[12 + 2 * j2] + phv[2 * j2], h[13 + 2 * j2] + phv[2 * j2 + 1]);
  }

  if (q == 0) {
    zbuf[n] = z;
    out[2 * (size_t)Npts + n] = (float)cnt;
  }

  // reduction for zmean / znorm (count each point once: q==0 lanes only)
  float rz = (q == 0 && z > 0.f) ? z : 0.f;
  float rz2 = rz * rz;
  float rcn = (q == 0 && z > 0.f) ? 1.f : 0.f;
#pragma unroll
  for (int off = 32; off > 0; off >>= 1) {
    rz += __shfl_down(rz, off);
    rz2 += __shfl_down(rz2, off);
    rcn += __shfl_down(rcn, off);
  }
  int wid = threadIdx.x >> 6, lid = threadIdx.x & 63;
  if (lid == 0) {
    redl[0][wid] = rz;
    redl[1][wid] = rz2;
    redl[2][wid] = rcn;
  }
  __syncthreads();
  if (threadIdx.x == 0) {
    float a = 0.f, b = 0.f, c = 0.f;
#pragma unroll
    for (int w = 0; w < 4; w++) {
      a += redl[0][w];
      b += redl[1][w];
      c += redl[2][w];
    }
    atomicAdd(&red[0], (double)a);
    atomicAdd(&red[1], (double)b);
    atomicAdd(&red[2], (double)c);
  }
}

// ---------------- 3) finalize: zn + relu + heads ---------------------------
__global__ __launch_bounds__(256) void final_kernel(
    const float* __restrict__ zbuf, const unsigned* __restrict__ hp,
    const float* __restrict__ W_sp, const float* __restrict__ W_t,
    const float* __restrict__ b_t, const float* __restrict__ W_o,
    const float* __restrict__ b_o, const double* __restrict__ red,
    float* __restrict__ out) {
  __shared__ float wz[Cc], wt[Cc], wo[Cc];
  __shared__ float bt, bo, s_zmean, s_izn;
  if (threadIdx.x < Cc) {
    wz[threadIdx.x] = W_sp[24 * Cc + threadIdx.x];
    wt[threadIdx.x] = W_t[threadIdx.x];
    wo[threadIdx.x] = W_o[threadIdx.x];
  }
  if (threadIdx.x == 0) {
    bt = b_t[0];
    bo = b_o[0];
    double sz = red[0], sz2 = red[1], cd = red[2];
    double npos = (cd > 0.0) ? cd : 1.0;
    double zmean = sz / npos;
    double var = sz2 - 2.0 * zmean * sz + cd * zmean * zmean;
    if (var < 0.0) var = 0.0;
    double znorm = sqrt(var) + 1e-5;
    s_zmean = (float)zmean;
    s_izn = (float)(1.0 / znorm);
  }
  __syncthreads();
  int n = blockIdx.x * 256 + threadIdx.x;
  float z = zbuf[n];
  float zn = (z > 0.f) ? (z - s_zmean) * s_izn : 0.f;
  float tsdf = bt, occ = bo;
#pragma unroll
  for (int j2 = 0; j2 < 12; j2++) {
    unsigned u = hp[(size_t)j2 * Npts + n];
    float2 f = __half22float2(*(const __half2*)&u);
    float h0 = fmaxf(f.x + zn * wz[2 * j2], 0.f);
    float h1 = fmaxf(f.y + zn * wz[2 * j2 + 1], 0.f);
    tsdf += h0 * wt[2 * j2] + h1 * wt[2 * j2 + 1];
    occ += h0 * wo[2 * j2] + h1 * wo[2 * j2 + 1];
  }
  ((float2*)out)[n] = make_float2(tsdf, occ);
}

// ---------------- launch ---------------------------------------------------
extern "C" void kernel_launch(void* const* d_in, const int* in_sizes, int n_in,
                              void* d_out, int out_size, void* d_ws,
                              size_t ws_size, hipStream_t stream) {
  const float* pre_feat = (const float*)d_in[0];
  const int* pre_coords = (const int*)d_in[1];
  const float* feats = (const float*)d_in[2];
  const float* KRcam = (const float*)d_in[3];
  const float* vol_origin = (const float*)d_in[4];
  const float* w2ac = (const float*)d_in[5];
  const float* W_sp = (const float*)d_in[6];
  const float* b_sp = (const float*)d_in[7];
  const float* W_t = (const float*)d_in[8];
  const float* b_t = (const float*)d_in[9];
  const float* W_o = (const float*)d_in[10];
  const float* b_o = (const float*)d_in[11];

  float* out = (float*)d_out;
  char* ws = (char*)d_ws;
  double* red = (double*)ws;
  uint4* tf = (uint4*)(ws + OFF_TF);
  float* pre_h = (float*)(ws + OFF_PREH);
  unsigned* hp = (unsigned*)(ws + OFF_HP);
  float* zbuf = (float*)(ws + OFF_Z);

  prep_kernel<<<Vv * 300 + Mpts / 256, 256, 0, stream>>>(feats, pre_feat, W_sp,
                                                         b_sp, tf, pre_h, red);
  main_kernel<<<(2 * Npts) / 256, 256, 0, stream>>>(pre_coords, tf, KRcam,
                                                    vol_origin, w2ac, W_sp,
                                                    pre_h, out, hp, zbuf, red);
  final_kernel<<<Npts / 256, 256, 0, stream>>>(zbuf, hp, W_sp, W_t, b_t, W_o,
                                               b_o, red, out);
}

// Round 4
// 144.205 us; speedup vs baseline: 1.7812x; 1.7812x over previous
//
#include <hip/hip_runtime.h>
#include <hip/hip_fp16.h>

#define Mpts 32768
#define Vv 9
#define Cc 24
#define Hh 120
#define Ww 160
#define Npts (Mpts * 8)          // 262144
#define PIX (Hh * Ww)            // 19200
#define VOXEL 0.04f

#define NSLOT 64                 // sharded reduction slots (1 cache line each)

// ---------------- workspace layout (bytes) ----------------
// [0, NSLOT*64)  : NSLOT slots x 8 doubles {sum_z, sum_z2, pos_cnt, pad...}
// OFF_TF    : tf = feats (V,H,W) x 32B/pixel fp8(24ch+8pad) : 5529600 B
// OFF_PREH  : pre_h (M,24) f32                               : 3145728 B
// OFF_HP    : hp (12,N) uint (= half2 channel pairs)         : 12582912 B
// OFF_Z     : zbuf (N) f32                                   : 1048576 B
#define OFF_TF    (NSLOT * 64)
#define OFF_PREH  (OFF_TF + Vv * PIX * 32)
#define OFF_HP    (OFF_PREH + Mpts * Cc * 4)
#define OFF_Z     (OFF_HP + Npts * Cc * 2)

typedef __attribute__((ext_vector_type(2))) float f32x2;
typedef __attribute__((ext_vector_type(4))) float f32x4;
typedef __attribute__((ext_vector_type(4))) int i32x4;

__device__ __forceinline__ unsigned pack2h(float a, float b) {
  __half2 h = __floats2half2_rn(a, b);
  return *(unsigned*)&h;
}

// pack 4 floats -> 4 fp8 e4m3 in one uint
__device__ __forceinline__ unsigned pack4fp8(float a, float b, float c,
                                             float d) {
  int u = __builtin_amdgcn_cvt_pk_fp8_f32(a, b, 0, false);
  u = __builtin_amdgcn_cvt_pk_fp8_f32(c, d, u, true);
  return (unsigned)u;
}

// ---------------- 1) prep: feats -> fp8 tf, pre_h gemm, zero red -----------
// Small static LDS (11.3 KB) so tf blocks keep high occupancy.
__global__ __launch_bounds__(256) void prep_kernel(
    const float* __restrict__ feats, const float* __restrict__ pre_feat,
    const float* __restrict__ W_sp, const float* __restrict__ b_sp,
    uint4* __restrict__ tf, float* __restrict__ pre_h,
    double* __restrict__ red) {
  __shared__ float tile[64][Cc + 1];
  __shared__ float Wl[50 * Cc];
  __shared__ float bl[Cc];
  int blk = blockIdx.x;
  if (blk == 0) {  // zero all NSLOT*8 doubles
    red[threadIdx.x] = 0.0;
    red[threadIdx.x + 256] = 0.0;
  }

  if (blk < Vv * 300) {
    int v = blk / 300;
    int p0 = (blk % 300) * 64;
    const float* src = feats + (size_t)v * (Cc * PIX);
    for (int i = threadIdx.x; i < Cc * 64; i += 256) {
      int c = i >> 6, p = i & 63;
      tile[p][c] = src[c * PIX + p0 + p];
    }
    __syncthreads();
    uint4* dst = tf + ((size_t)v * PIX + p0) * 2;
    if (threadIdx.x < 128) {
      int p = threadIdx.x >> 1, sel = threadIdx.x & 1;
      const float* t = &tile[p][0];
      uint4 u;
      if (sel == 0) {
        u.x = pack4fp8(t[0], t[1], t[2], t[3]);
        u.y = pack4fp8(t[4], t[5], t[6], t[7]);
        u.z = pack4fp8(t[8], t[9], t[10], t[11]);
        u.w = pack4fp8(t[12], t[13], t[14], t[15]);
      } else {
        u.x = pack4fp8(t[16], t[17], t[18], t[19]);
        u.y = pack4fp8(t[20], t[21], t[22], t[23]);
        u.z = 0;
        u.w = 0;
      }
      dst[p * 2 + sel] = u;
    }
  } else {
    int mb = blk - Vv * 300;
    for (int i = threadIdx.x; i < 50 * Cc; i += 256) Wl[i] = W_sp[25 * Cc + i];
    if (threadIdx.x < Cc) bl[threadIdx.x] = b_sp[threadIdx.x];
    __syncthreads();
    int m = mb * 256 + threadIdx.x;
    float acc[Cc];
#pragma unroll
    for (int j = 0; j < Cc; j++) acc[j] = bl[j];
    const f32x2* pf = (const f32x2*)(pre_feat + (size_t)m * 50);
#pragma unroll 5
    for (int k = 0; k < 25; k++) {
      f32x2 x = __builtin_nontemporal_load(pf + k);
#pragma unroll
      for (int j = 0; j < Cc; j++)
        acc[j] += x.x * Wl[(2 * k) * Cc + j] + x.y * Wl[(2 * k + 1) * Cc + j];
    }
    f32x4* o4 = (f32x4*)(pre_h + (size_t)m * Cc);
#pragma unroll
    for (int t = 0; t < 6; t++) {
      f32x4 v4 = {acc[4 * t], acc[4 * t + 1], acc[4 * t + 2], acc[4 * t + 3]};
      __builtin_nontemporal_store(v4, o4 + t);
    }
  }
}

// acc[0..15] += w * fp8x16(A)
__device__ __forceinline__ void acc16(uint4 A, float w, float* acc) {
#pragma unroll
  for (int t = 0; t < 4; t++) {
    unsigned u = ((const unsigned*)&A)[t];
    f32x2 f0 = __builtin_amdgcn_cvt_pk_f32_fp8((int)u, false);
    f32x2 f1 = __builtin_amdgcn_cvt_pk_f32_fp8((int)u, true);
    acc[4 * t + 0] += w * f0.x;
    acc[4 * t + 1] += w * f0.y;
    acc[4 * t + 2] += w * f1.x;
    acc[4 * t + 3] += w * f1.y;
  }
}
// acc[0..7] += w * fp8x8(ux,uy)
__device__ __forceinline__ void acc8v(unsigned ux, unsigned uy, float w,
                                      float* acc) {
  f32x2 f0 = __builtin_amdgcn_cvt_pk_f32_fp8((int)ux, false);
  f32x2 f1 = __builtin_amdgcn_cvt_pk_f32_fp8((int)ux, true);
  f32x2 f2 = __builtin_amdgcn_cvt_pk_f32_fp8((int)uy, false);
  f32x2 f3 = __builtin_amdgcn_cvt_pk_f32_fp8((int)uy, true);
  acc[0] += w * f0.x;
  acc[1] += w * f0.y;
  acc[2] += w * f1.x;
  acc[3] += w * f1.y;
  acc[4] += w * f2.x;
  acc[5] += w * f2.y;
  acc[6] += w * f3.x;
  acc[7] += w * f3.y;
}

// ---------------- 2) main: 1 thread/point, branchy gathers -----------------
// R0 structure (best measured): branchy view loop, per-wave gather locality,
// plus NT streaming stores and sharded reduction atomics.
__global__ __launch_bounds__(256) void main_kernel(
    const int* __restrict__ pre_coords, const uint4* __restrict__ tfq,
    const float* __restrict__ KRcam, const float* __restrict__ vol_origin,
    const float* __restrict__ w2ac, const float* __restrict__ W_sp,
    const float* __restrict__ pre_h, float* __restrict__ out,
    unsigned* __restrict__ hp, float* __restrict__ zbuf,
    double* __restrict__ red) {
  __shared__ float KR[Vv * 12];
  __shared__ float w2a[12];
  __shared__ float orig[3];
  __shared__ float redl[3][4];
  for (int i = threadIdx.x; i < Vv * 12; i += 256) {
    int v = i / 12, r = i - v * 12;
    KR[i] = KRcam[v * 16 + r];
  }
  if (threadIdx.x < 12) w2a[threadIdx.x] = w2ac[threadIdx.x];
  if (threadIdx.x < 3) orig[threadIdx.x] = vol_origin[threadIdx.x];
  __syncthreads();

  int n = blockIdx.x * 256 + threadIdx.x;
  int m = n >> 3, o = n & 7;
  i32x4 pc = __builtin_nontemporal_load((const i32x4*)pre_coords + m);
  int cx = pc.y + ((0xB2 >> o) & 1);
  int cy = pc.z + ((0xD4 >> o) & 1);
  int cz = pc.w + ((0xE8 >> o) & 1);
  float wx0 = (float)cx * VOXEL + orig[0];
  float wy0 = (float)cy * VOXEL + orig[1];
  float wz0 = (float)cz * VOXEL + orig[2];

  {  // r_coords
    float camx = w2a[0] * wx0 + w2a[1] * wy0 + w2a[2] * wz0 + w2a[3];
    float camy = w2a[4] * wx0 + w2a[5] * wy0 + w2a[6] * wz0 + w2a[7];
    float camz = w2a[8] * wx0 + w2a[9] * wy0 + w2a[10] * wz0 + w2a[11];
    f32x4 rc = {camx, camy, camz, (float)pc.x};
    __builtin_nontemporal_store(rc, (f32x4*)(out + 3 * (size_t)Npts) + n);
  }

  float acc[Cc];
#pragma unroll
  for (int c = 0; c < Cc; c++) acc[c] = 0.f;
  float zsum = 0.f;
  int cnt = 0;

  for (int v = 0; v < Vv; v++) {
    const float* kr = &KR[v * 12];
    float ix = kr[0] * wx0 + kr[1] * wy0 + kr[2] * wz0 + kr[3];
    float iy = kr[4] * wx0 + kr[5] * wy0 + kr[6] * wz0 + kr[7];
    float iz = kr[8] * wx0 + kr[9] * wy0 + kr[10] * wz0 + kr[11];
    float sz = (fabsf(iz) > 1e-9f) ? iz : 1e-9f;
    float px = ix / sz;
    float py = iy / sz;
    bool msk = (px >= 0.f) && (px <= (float)(Ww - 1)) && (py >= 0.f) &&
               (py <= (float)(Hh - 1)) && (iz > 0.f);
    if (msk) {
      int x0 = (int)floorf(px), y0 = (int)floorf(py);
      int xs = min(x0, Ww - 2), ys = min(y0, Hh - 2);
      float wx = px - (float)xs, wy = py - (float)ys;
      float w00 = (1.f - wx) * (1.f - wy);
      float w10 = wx * (1.f - wy);
      float w01 = (1.f - wx) * wy;
      float w11 = wx * wy;
      const uint4* p = tfq + ((size_t)(v * PIX + ys * Ww + xs)) * 2;
      const uint4* q = p + Ww * 2;
      uint4 A = p[0], B = p[2], C = q[0], D = q[2];
      uint2 Ab = *(const uint2*)(p + 1), Bb = *(const uint2*)(p + 3);
      uint2 Cb = *(const uint2*)(q + 1), Db = *(const uint2*)(q + 3);
      acc16(A, w00, &acc[0]);
      acc8v(Ab.x, Ab.y, w00, &acc[16]);
      acc16(B, w10, &acc[0]);
      acc8v(Bb.x, Bb.y, w10, &acc[16]);
      acc16(C, w01, &acc[0]);
      acc8v(Cb.x, Cb.y, w01, &acc[16]);
      acc16(D, w11, &acc[0]);
      acc8v(Db.x, Db.y, w11, &acc[16]);
      zsum += iz;
      cnt++;
    }
  }

  float denom = fmaxf((float)cnt, 1.f);
  float invd = 1.f / denom;
  float z = zsum * invd;

  // h = pre_h[m] + (acc*invd) @ W_sp[0:24,:]  (W_sp: uniform scalar loads)
  float h[Cc];
  {
    const f32x4* ph4 = (const f32x4*)(pre_h + (size_t)m * Cc);
#pragma unroll
    for (int t = 0; t < 6; t++) {
      f32x4 v4 = __builtin_nontemporal_load(ph4 + t);
      h[4 * t + 0] = v4.x;
      h[4 * t + 1] = v4.y;
      h[4 * t + 2] = v4.z;
      h[4 * t + 3] = v4.w;
    }
  }
#pragma unroll
  for (int c = 0; c < Cc; c++) {
    float f = acc[c] * invd;
#pragma unroll
    for (int j = 0; j < Cc; j++) h[j] += f * W_sp[c * Cc + j];
  }
#pragma unroll
  for (int j2 = 0; j2 < 12; j2++)
    __builtin_nontemporal_store(pack2h(h[2 * j2], h[2 * j2 + 1]),
                                hp + (size_t)j2 * Npts + n);

  __builtin_nontemporal_store(z, zbuf + n);
  __builtin_nontemporal_store((float)cnt, out + 2 * (size_t)Npts + n);

  // reduction for zmean / znorm
  float rz = (z > 0.f) ? z : 0.f;
  float rz2 = rz * rz;
  float rcn = (z > 0.f) ? 1.f : 0.f;
#pragma unroll
  for (int off = 32; off > 0; off >>= 1) {
    rz += __shfl_down(rz, off);
    rz2 += __shfl_down(rz2, off);
    rcn += __shfl_down(rcn, off);
  }
  int wid = threadIdx.x >> 6, lid = threadIdx.x & 63;
  if (lid == 0) {
    redl[0][wid] = rz;
    redl[1][wid] = rz2;
    redl[2][wid] = rcn;
  }
  __syncthreads();
  if (threadIdx.x == 0) {
    float a = 0.f, b = 0.f, c = 0.f;
#pragma unroll
    for (int w = 0; w < 4; w++) {
      a += redl[0][w];
      b += redl[1][w];
      c += redl[2][w];
    }
    // sharded: 64 line-spaced slots -> 64 parallel TCC slices
    double* slot = red + (size_t)(blockIdx.x & (NSLOT - 1)) * 8;
    atomicAdd(&slot[0], (double)a);
    atomicAdd(&slot[1], (double)b);
    atomicAdd(&slot[2], (double)c);
  }
}

// ---------------- 3) finalize: reduce slots + zn + relu + heads ------------
__global__ __launch_bounds__(256) void final_kernel(
    const float* __restrict__ zbuf, const unsigned* __restrict__ hp,
    const float* __restrict__ W_sp, const float* __restrict__ W_t,
    const float* __restrict__ b_t, const float* __restrict__ W_o,
    const float* __restrict__ b_o, const double* __restrict__ red,
    float* __restrict__ out) {
  __shared__ float wz[Cc], wt[Cc], wo[Cc];
  __shared__ float bt, bo, s_zmean, s_izn;
  if (threadIdx.x < Cc) {
    wz[threadIdx.x] = W_sp[24 * Cc + threadIdx.x];
    wt[threadIdx.x] = W_t[threadIdx.x];
    wo[threadIdx.x] = W_o[threadIdx.x];
  }
  if (threadIdx.x == 64) {
    bt = b_t[0];
    bo = b_o[0];
  }
  if (threadIdx.x < NSLOT) {  // one wave reduces the 64 slots
    double a = red[(size_t)threadIdx.x * 8 + 0];
    double b = red[(size_t)threadIdx.x * 8 + 1];
    double c = red[(size_t)threadIdx.x * 8 + 2];
#pragma unroll
    for (int off = 32; off > 0; off >>= 1) {
      a += __shfl_down(a, off);
      b += __shfl_down(b, off);
      c += __shfl_down(c, off);
    }
    if (threadIdx.x == 0) {
      double npos = (c > 0.0) ? c : 1.0;
      double zmean = a / npos;
      double var = b - 2.0 * zmean * a + c * zmean * zmean;
      if (var < 0.0) var = 0.0;
      double znorm = sqrt(var) + 1e-5;
      s_zmean = (float)zmean;
      s_izn = (float)(1.0 / znorm);
    }
  }
  __syncthreads();
  int n = blockIdx.x * 256 + threadIdx.x;
  float z = __builtin_nontemporal_load(zbuf + n);
  float zn = (z > 0.f) ? (z - s_zmean) * s_izn : 0.f;
  float tsdf = bt, occ = bo;
#pragma unroll
  for (int j2 = 0; j2 < 12; j2++) {
    unsigned u = __builtin_nontemporal_load(hp + (size_t)j2 * Npts + n);
    float2 f = __half22float2(*(const __half2*)&u);
    float h0 = fmaxf(f.x + zn * wz[2 * j2], 0.f);
    float h1 = fmaxf(f.y + zn * wz[2 * j2 + 1], 0.f);
    tsdf += h0 * wt[2 * j2] + h1 * wt[2 * j2 + 1];
    occ += h0 * wo[2 * j2] + h1 * wo[2 * j2 + 1];
  }
  f32x2 o2 = {tsdf, occ};
  __builtin_nontemporal_store(o2, (f32x2*)out + n);
}

// ---------------- launch ---------------------------------------------------
extern "C" void kernel_launch(void* const* d_in, const int* in_sizes, int n_in,
                              void* d_out, int out_size, void* d_ws,
                              size_t ws_size, hipStream_t stream) {
  const float* pre_feat = (const float*)d_in[0];
  const int* pre_coords = (const int*)d_in[1];
  const float* feats = (const float*)d_in[2];
  const float* KRcam = (const float*)d_in[3];
  const float* vol_origin = (const float*)d_in[4];
  const float* w2ac = (const float*)d_in[5];
  const float* W_sp = (const float*)d_in[6];
  const float* b_sp = (const float*)d_in[7];
  const float* W_t = (const float*)d_in[8];
  const float* b_t = (const float*)d_in[9];
  const float* W_o = (const float*)d_in[10];
  const float* b_o = (const float*)d_in[11];

  float* out = (float*)d_out;
  char* ws = (char*)d_ws;
  double* red = (double*)ws;
  uint4* tf = (uint4*)(ws + OFF_TF);
  float* pre_h = (float*)(ws + OFF_PREH);
  unsigned* hp = (unsigned*)(ws + OFF_HP);
  float* zbuf = (float*)(ws + OFF_Z);

  prep_kernel<<<Vv * 300 + Mpts / 256, 256, 0, stream>>>(feats, pre_feat, W_sp,
                                                         b_sp, tf, pre_h, red);
  main_kernel<<<Npts / 256, 256, 0, stream>>>(pre_coords, tf, KRcam,
                                              vol_origin, w2ac, W_sp, pre_h,
                                              out, hp, zbuf, red);
  final_kernel<<<Npts / 256, 256, 0, stream>>>(zbuf, hp, W_sp, W_t, b_t, W_o,
                                               b_o, red, out);
}

// Round 5
// 141.542 us; speedup vs baseline: 1.8147x; 1.0188x over previous
//
#include <hip/hip_runtime.h>
#include <hip/hip_fp16.h>

#define Mpts 32768
#define Vv 9
#define Cc 24
#define Hh 120
#define Ww 160
#define Npts (Mpts * 8)          // 262144
#define PIX (Hh * Ww)            // 19200
#define VOXEL 0.04f

#define NB_TF   (Vv * 300)       // 2700 tf-convert blocks
#define NB_GEMM (Mpts / 256)     // 128 pre_h gemm blocks
#define NB_Z    (Npts / 256)     // 1024 z-stat blocks (and main blocks)

// ---------------- workspace layout (bytes) ----------------
// [0, 24576)  : red[NB_Z][3] doubles — per-block z partials (write-only slots,
//               no atomics, no zeroing needed: every slot written exactly once)
// OFF_TF      : tf = feats (V,H,W) x 32B/pixel fp8(24ch+8pad) : 5529600 B
// OFF_PREH    : pre_h (M,24) f32                               : 3145728 B
#define OFF_TF    32768
#define OFF_PREH  (OFF_TF + Vv * PIX * 32)

typedef __attribute__((ext_vector_type(2))) float f32x2;
typedef __attribute__((ext_vector_type(4))) float f32x4;
typedef __attribute__((ext_vector_type(4))) int i32x4;

// pack 4 floats -> 4 fp8 e4m3 in one uint
__device__ __forceinline__ unsigned pack4fp8(float a, float b, float c,
                                             float d) {
  int u = __builtin_amdgcn_cvt_pk_fp8_f32(a, b, 0, false);
  u = __builtin_amdgcn_cvt_pk_fp8_f32(c, d, u, true);
  return (unsigned)u;
}

// ---------------- 1) prep: tf-convert | pre_h gemm | z-stat pass -----------
__global__ __launch_bounds__(256) void prep_kernel(
    const float* __restrict__ feats, const float* __restrict__ pre_feat,
    const float* __restrict__ W_sp, const float* __restrict__ b_sp,
    const int* __restrict__ pre_coords, const float* __restrict__ KRcam,
    const float* __restrict__ vol_origin, uint4* __restrict__ tf,
    float* __restrict__ pre_h, double* __restrict__ red) {
  __shared__ float tile[64][Cc + 1];   // tf path (6.4 KB)
  __shared__ float Wl[50 * Cc];        // gemm path (4.8 KB)
  __shared__ float bl[Cc];
  __shared__ float KRs[Vv * 12];       // z path
  __shared__ float origs[3];
  __shared__ float redl[3][4];
  int blk = blockIdx.x;

  if (blk < NB_TF) {
    // ---- feats(f32, C-major) -> tf(fp8, pixel-major 32B) ----
    int v = blk / 300;
    int p0 = (blk % 300) * 64;
    const float* src = feats + (size_t)v * (Cc * PIX);
    for (int i = threadIdx.x; i < Cc * 64; i += 256) {
      int c = i >> 6, p = i & 63;
      tile[p][c] = __builtin_nontemporal_load(src + c * PIX + p0 + p);
    }
    __syncthreads();
    uint4* dst = tf + ((size_t)v * PIX + p0) * 2;
    if (threadIdx.x < 128) {
      int p = threadIdx.x >> 1, sel = threadIdx.x & 1;
      const float* t = &tile[p][0];
      uint4 u;
      if (sel == 0) {
        u.x = pack4fp8(t[0], t[1], t[2], t[3]);
        u.y = pack4fp8(t[4], t[5], t[6], t[7]);
        u.z = pack4fp8(t[8], t[9], t[10], t[11]);
        u.w = pack4fp8(t[12], t[13], t[14], t[15]);
      } else {
        u.x = pack4fp8(t[16], t[17], t[18], t[19]);
        u.y = pack4fp8(t[20], t[21], t[22], t[23]);
        u.z = 0;
        u.w = 0;
      }
      dst[p * 2 + sel] = u;
    }
  } else if (blk < NB_TF + NB_GEMM) {
    // ---- pre_h = pre_feat @ W_sp[25:75] + b ----
    int mb = blk - NB_TF;
    for (int i = threadIdx.x; i < 50 * Cc; i += 256) Wl[i] = W_sp[25 * Cc + i];
    if (threadIdx.x < Cc) bl[threadIdx.x] = b_sp[threadIdx.x];
    __syncthreads();
    int m = mb * 256 + threadIdx.x;
    float acc[Cc];
#pragma unroll
    for (int j = 0; j < Cc; j++) acc[j] = bl[j];
    const f32x2* pf = (const f32x2*)(pre_feat + (size_t)m * 50);
#pragma unroll 5
    for (int k = 0; k < 25; k++) {
      f32x2 x = __builtin_nontemporal_load(pf + k);
#pragma unroll
      for (int j = 0; j < Cc; j++)
        acc[j] += x.x * Wl[(2 * k) * Cc + j] + x.y * Wl[(2 * k + 1) * Cc + j];
    }
    f32x4* o4 = (f32x4*)(pre_h + (size_t)m * Cc);
#pragma unroll
    for (int t = 0; t < 6; t++) {
      f32x4 v4 = {acc[4 * t], acc[4 * t + 1], acc[4 * t + 2], acc[4 * t + 3]};
      o4[t] = v4;
    }
  } else {
    // ---- z-stat pass: projections only, per-block partial -> private slot --
    int zblk = blk - (NB_TF + NB_GEMM);
    for (int i = threadIdx.x; i < Vv * 12; i += 256) {
      int v = i / 12, r = i - v * 12;
      KRs[i] = KRcam[v * 16 + r];
    }
    if (threadIdx.x < 3) origs[threadIdx.x] = vol_origin[threadIdx.x];
    __syncthreads();
    int n = zblk * 256 + threadIdx.x;
    int m = n >> 3, o = n & 7;
    i32x4 pc = __builtin_nontemporal_load((const i32x4*)pre_coords + m);
    int cx = pc.y + ((0xB2 >> o) & 1);
    int cy = pc.z + ((0xD4 >> o) & 1);
    int cz = pc.w + ((0xE8 >> o) & 1);
    float wx0 = (float)cx * VOXEL + origs[0];
    float wy0 = (float)cy * VOXEL + origs[1];
    float wz0 = (float)cz * VOXEL + origs[2];
    float zsum = 0.f;
    int cnt = 0;
    for (int v = 0; v < Vv; v++) {
      const float* kr = &KRs[v * 12];
      float ix = kr[0] * wx0 + kr[1] * wy0 + kr[2] * wz0 + kr[3];
      float iy = kr[4] * wx0 + kr[5] * wy0 + kr[6] * wz0 + kr[7];
      float iz = kr[8] * wx0 + kr[9] * wy0 + kr[10] * wz0 + kr[11];
      float sz = (fabsf(iz) > 1e-9f) ? iz : 1e-9f;
      float px = ix / sz;
      float py = iy / sz;
      bool msk = (px >= 0.f) && (px <= (float)(Ww - 1)) && (py >= 0.f) &&
                 (py <= (float)(Hh - 1)) && (iz > 0.f);
      if (msk) {
        zsum += iz;
        cnt++;
      }
    }
    float denom = fmaxf((float)cnt, 1.f);
    float z = zsum / denom;
    float rz = (z > 0.f) ? z : 0.f;
    float rz2 = rz * rz;
    float rcn = (z > 0.f) ? 1.f : 0.f;
#pragma unroll
    for (int off = 32; off > 0; off >>= 1) {
      rz += __shfl_down(rz, off);
      rz2 += __shfl_down(rz2, off);
      rcn += __shfl_down(rcn, off);
    }
    int wid = threadIdx.x >> 6, lid = threadIdx.x & 63;
    if (lid == 0) {
      redl[0][wid] = rz;
      redl[1][wid] = rz2;
      redl[2][wid] = rcn;
    }
    __syncthreads();
    if (threadIdx.x == 0) {
      float a = 0.f, b = 0.f, c = 0.f;
#pragma unroll
      for (int w = 0; w < 4; w++) {
        a += redl[0][w];
        b += redl[1][w];
        c += redl[2][w];
      }
      double* r3 = red + (size_t)zblk * 3;
      r3[0] = (double)a;
      r3[1] = (double)b;
      r3[2] = (double)c;
    }
  }
}

// acc[0..15] += w * fp8x16(A)
__device__ __forceinline__ void acc16(uint4 A, float w, float* acc) {
#pragma unroll
  for (int t = 0; t < 4; t++) {
    unsigned u = ((const unsigned*)&A)[t];
    f32x2 f0 = __builtin_amdgcn_cvt_pk_f32_fp8((int)u, false);
    f32x2 f1 = __builtin_amdgcn_cvt_pk_f32_fp8((int)u, true);
    acc[4 * t + 0] += w * f0.x;
    acc[4 * t + 1] += w * f0.y;
    acc[4 * t + 2] += w * f1.x;
    acc[4 * t + 3] += w * f1.y;
  }
}
// acc[0..7] += w * fp8x8(ux,uy)
__device__ __forceinline__ void acc8v(unsigned ux, unsigned uy, float w,
                                      float* acc) {
  f32x2 f0 = __builtin_amdgcn_cvt_pk_f32_fp8((int)ux, false);
  f32x2 f1 = __builtin_amdgcn_cvt_pk_f32_fp8((int)ux, true);
  f32x2 f2 = __builtin_amdgcn_cvt_pk_f32_fp8((int)uy, false);
  f32x2 f3 = __builtin_amdgcn_cvt_pk_f32_fp8((int)uy, true);
  acc[0] += w * f0.x;
  acc[1] += w * f0.y;
  acc[2] += w * f1.x;
  acc[3] += w * f1.y;
  acc[4] += w * f2.x;
  acc[5] += w * f2.y;
  acc[6] += w * f3.x;
  acc[7] += w * f3.y;
}

// ---------------- 2) main: gather + h + FUSED finalize ---------------------
// z-stats are already complete in red[]; each block reduces the 1024 slots
// (L2-hot, 24 KB) once, then h never leaves registers: relu+heads inline.
__global__ __launch_bounds__(256) void main_kernel(
    const int* __restrict__ pre_coords, const uint4* __restrict__ tfq,
    const float* __restrict__ KRcam, const float* __restrict__ vol_origin,
    const float* __restrict__ w2ac, const float* __restrict__ W_sp,
    const float* __restrict__ W_t, const float* __restrict__ b_t,
    const float* __restrict__ W_o, const float* __restrict__ b_o,
    const float* __restrict__ pre_h, float* __restrict__ out,
    const double* __restrict__ red) {
  __shared__ float KR[Vv * 12];
  __shared__ float w2a[12];
  __shared__ float orig[3];
  __shared__ double dredl[3][4];
  __shared__ float s_zmean, s_izn;
  for (int i = threadIdx.x; i < Vv * 12; i += 256) {
    int v = i / 12, r = i - v * 12;
    KR[i] = KRcam[v * 16 + r];
  }
  if (threadIdx.x < 12) w2a[threadIdx.x] = w2ac[threadIdx.x];
  if (threadIdx.x < 3) orig[threadIdx.x] = vol_origin[threadIdx.x];

  {  // reduce the 1024 per-block partials -> zmean, 1/znorm
    double a = 0.0, b = 0.0, c = 0.0;
    for (int s = threadIdx.x; s < NB_Z; s += 256) {
      const double* r3 = red + (size_t)s * 3;
      a += r3[0];
      b += r3[1];
      c += r3[2];
    }
#pragma unroll
    for (int off = 32; off > 0; off >>= 1) {
      a += __shfl_down(a, off);
      b += __shfl_down(b, off);
      c += __shfl_down(c, off);
    }
    int wid = threadIdx.x >> 6, lid = threadIdx.x & 63;
    if (lid == 0) {
      dredl[0][wid] = a;
      dredl[1][wid] = b;
      dredl[2][wid] = c;
    }
    __syncthreads();
    if (threadIdx.x == 0) {
      double A = 0.0, B = 0.0, C = 0.0;
#pragma unroll
      for (int w = 0; w < 4; w++) {
        A += dredl[0][w];
        B += dredl[1][w];
        C += dredl[2][w];
      }
      double npos = (C > 0.0) ? C : 1.0;
      double zmean = A / npos;
      double var = B - 2.0 * zmean * A + C * zmean * zmean;
      if (var < 0.0) var = 0.0;
      double znorm = sqrt(var) + 1e-5;
      s_zmean = (float)zmean;
      s_izn = (float)(1.0 / znorm);
    }
  }
  __syncthreads();

  int n = blockIdx.x * 256 + threadIdx.x;
  int m = n >> 3, o = n & 7;
  i32x4 pc = __builtin_nontemporal_load((const i32x4*)pre_coords + m);
  int cx = pc.y + ((0xB2 >> o) & 1);
  int cy = pc.z + ((0xD4 >> o) & 1);
  int cz = pc.w + ((0xE8 >> o) & 1);
  float wx0 = (float)cx * VOXEL + orig[0];
  float wy0 = (float)cy * VOXEL + orig[1];
  float wz0 = (float)cz * VOXEL + orig[2];

  {  // r_coords
    float camx = w2a[0] * wx0 + w2a[1] * wy0 + w2a[2] * wz0 + w2a[3];
    float camy = w2a[4] * wx0 + w2a[5] * wy0 + w2a[6] * wz0 + w2a[7];
    float camz = w2a[8] * wx0 + w2a[9] * wy0 + w2a[10] * wz0 + w2a[11];
    f32x4 rc = {camx, camy, camz, (float)pc.x};
    __builtin_nontemporal_store(rc, (f32x4*)(out + 3 * (size_t)Npts) + n);
  }

  float acc[Cc];
#pragma unroll
  for (int c = 0; c < Cc; c++) acc[c] = 0.f;
  float zsum = 0.f;
  int cnt = 0;

  for (int v = 0; v < Vv; v++) {
    const float* kr = &KR[v * 12];
    float ix = kr[0] * wx0 + kr[1] * wy0 + kr[2] * wz0 + kr[3];
    float iy = kr[4] * wx0 + kr[5] * wy0 + kr[6] * wz0 + kr[7];
    float iz = kr[8] * wx0 + kr[9] * wy0 + kr[10] * wz0 + kr[11];
    float sz = (fabsf(iz) > 1e-9f) ? iz : 1e-9f;
    float px = ix / sz;
    float py = iy / sz;
    bool msk = (px >= 0.f) && (px <= (float)(Ww - 1)) && (py >= 0.f) &&
               (py <= (float)(Hh - 1)) && (iz > 0.f);
    if (msk) {
      int x0 = (int)floorf(px), y0 = (int)floorf(py);
      int xs = min(x0, Ww - 2), ys = min(y0, Hh - 2);
      float wx = px - (float)xs, wy = py - (float)ys;
      float w00 = (1.f - wx) * (1.f - wy);
      float w10 = wx * (1.f - wy);
      float w01 = (1.f - wx) * wy;
      float w11 = wx * wy;
      const uint4* p = tfq + ((size_t)(v * PIX + ys * Ww + xs)) * 2;
      const uint4* q = p + Ww * 2;
      uint4 A = p[0], B = p[2], C = q[0], D = q[2];
      uint2 Ab = *(const uint2*)(p + 1), Bb = *(const uint2*)(p + 3);
      uint2 Cb = *(const uint2*)(q + 1), Db = *(const uint2*)(q + 3);
      acc16(A, w00, &acc[0]);
      acc8v(Ab.x, Ab.y, w00, &acc[16]);
      acc16(B, w10, &acc[0]);
      acc8v(Bb.x, Bb.y, w10, &acc[16]);
      acc16(C, w01, &acc[0]);
      acc8v(Cb.x, Cb.y, w01, &acc[16]);
      acc16(D, w11, &acc[0]);
      acc8v(Db.x, Db.y, w11, &acc[16]);
      zsum += iz;
      cnt++;
    }
  }

  float denom = fmaxf((float)cnt, 1.f);
  float invd = 1.f / denom;
  float z = zsum * invd;

  // h = pre_h[m] + (acc*invd) @ W_sp[0:24,:]  (W_sp: uniform scalar loads)
  float h[Cc];
  {
    const f32x4* ph4 = (const f32x4*)(pre_h + (size_t)m * Cc);
#pragma unroll
    for (int t = 0; t < 6; t++) {
      f32x4 v4 = ph4[t];
      h[4 * t + 0] = v4.x;
      h[4 * t + 1] = v4.y;
      h[4 * t + 2] = v4.z;
      h[4 * t + 3] = v4.w;
    }
  }
#pragma unroll
  for (int c = 0; c < Cc; c++) {
    float f = acc[c] * invd;
#pragma unroll
    for (int j = 0; j < Cc; j++) h[j] += f * W_sp[c * Cc + j];
  }

  // ---- fused finalize: zn channel + relu + heads, h never leaves regs ----
  float zn = (z > 0.f) ? (z - s_zmean) * s_izn : 0.f;
  float tsdf = b_t[0], occ = b_o[0];
#pragma unroll
  for (int j = 0; j < Cc; j++) {
    float hj = fmaxf(h[j] + zn * W_sp[24 * Cc + j], 0.f);
    tsdf += hj * W_t[j];
    occ += hj * W_o[j];
  }
  f32x2 o2 = {tsdf, occ};
  __builtin_nontemporal_store(o2, (f32x2*)out + n);
  __builtin_nontemporal_store((float)cnt, out + 2 * (size_t)Npts + n);
}

// ---------------- launch ---------------------------------------------------
extern "C" void kernel_launch(void* const* d_in, const int* in_sizes, int n_in,
                              void* d_out, int out_size, void* d_ws,
                              size_t ws_size, hipStream_t stream) {
  const float* pre_feat = (const float*)d_in[0];
  const int* pre_coords = (const int*)d_in[1];
  const float* feats = (const float*)d_in[2];
  const float* KRcam = (const float*)d_in[3];
  const float* vol_origin = (const float*)d_in[4];
  const float* w2ac = (const float*)d_in[5];
  const float* W_sp = (const float*)d_in[6];
  const float* b_sp = (const float*)d_in[7];
  const float* W_t = (const float*)d_in[8];
  const float* b_t = (const float*)d_in[9];
  const float* W_o = (const float*)d_in[10];
  const float* b_o = (const float*)d_in[11];

  float* out = (float*)d_out;
  char* ws = (char*)d_ws;
  double* red = (double*)ws;
  uint4* tf = (uint4*)(ws + OFF_TF);
  float* pre_h = (float*)(ws + OFF_PREH);

  prep_kernel<<<NB_TF + NB_GEMM + NB_Z, 256, 0, stream>>>(
      feats, pre_feat, W_sp, b_sp, pre_coords, KRcam, vol_origin, tf, pre_h,
      red);
  main_kernel<<<NB_Z, 256, 0, stream>>>(pre_coords, tf, KRcam, vol_origin,
                                        w2ac, W_sp, W_t, b_t, W_o, b_o, pre_h,
                                        out, red);
}